// Round 12
// baseline (263.245 us; speedup 1.0000x reference)
//
#include <hip/hip_runtime.h>
#include <hip/hip_bf16.h>
#include <math.h>

#define S_LEN 2048
#define DMODEL 2048
#define NH 16
#define NKVH 4
#define HDIM 128
#define WINDOW 1024

typedef __bf16 bf16;
typedef __bf16 bf16x8 __attribute__((ext_vector_type(8)));
typedef __bf16 bf16x4 __attribute__((ext_vector_type(4)));
typedef float floatx4 __attribute__((ext_vector_type(4)));

static __device__ __forceinline__ bf16x8 load_bf8(const bf16* p) {
    return *reinterpret_cast<const bf16x8*>(p);
}

// async 16B global->LDS (wave-uniform LDS base + lane*16)
static __device__ __forceinline__ void async16(const bf16* g, bf16* l) {
    __builtin_amdgcn_global_load_lds(
        (const __attribute__((address_space(1))) void*)g,
        (__attribute__((address_space(3))) void*)l, 16, 0, 0);
}

// -------- fp32 -> bf16 conversion of x ONLY ---------------------------------
// r12: weights no longer pre-converted. wo rides in attn (r10); wq/wk/wv are
// staged fp32->bf16 inside qkv's B-staging (T14 split). Convert shrinks to
// 16MB read + 8MB write (~4.5us).
__global__ __launch_bounds__(256) void convert_kernel(
    const float* __restrict__ x, bf16* __restrict__ xb) {
    for (int i = blockIdx.x * blockDim.x + threadIdx.x; i < 1048576;
         i += gridDim.x * blockDim.x) {
        float4 v = reinterpret_cast<const float4*>(x)[i];
        union { bf16 b[4]; ushort4 u; } t;
        t.b[0] = (bf16)v.x; t.b[1] = (bf16)v.y;
        t.b[2] = (bf16)v.z; t.b[3] = (bf16)v.w;
        reinterpret_cast<ushort4*>(xb)[i] = t.u;
    }
}

// ====== 64x128 tile, BK=64, dbuf GEMM body (r1-proven; gemm_out only) =======
#define GEMM_BODY()                                                            \
    __shared__ __align__(16) bf16 smem[2 * (64 + 128) * 64]; /* 48 KB */       \
    int tid = threadIdx.x;                                                     \
    int lane = tid & 63, wid = tid >> 6;                                       \
    int l15 = lane & 15, quad = lane >> 4;                                     \
    int rlocal = lane >> 3;                                                    \
    int scol = ((lane & 7) ^ rlocal) * 8;                                      \
    const bf16* gA = A + (size_t)(m0 + wid * 16 + rlocal) * K + scol;          \
    const bf16* gB = B + (size_t)(n0 + wid * 32 + rlocal) * K + scol;          \
    int ldsOfA = (wid * 16) * 64;                                               \
    int ldsOfB = (wid * 32) * 64;                                               \
    floatx4 acc[2][4];                                                         \
    _Pragma("unroll") for (int mi = 0; mi < 2; ++mi)                           \
        _Pragma("unroll") for (int ni = 0; ni < 4; ++ni)                       \
            acc[mi][ni] = floatx4{0.f, 0.f, 0.f, 0.f};                         \
    int mb = (wid & 1) * 32, nb = (wid >> 1) * 64;                             \
    _Pragma("unroll") for (int j = 0; j < 2; ++j)                              \
        async16(gA + (size_t)(j * 8) * K, smem + ldsOfA + j * 512);            \
    _Pragma("unroll") for (int j = 0; j < 4; ++j)                              \
        async16(gB + (size_t)(j * 8) * K, smem + 8192 + ldsOfB + j * 512);     \
    int buf = 0;                                                               \
    for (int k0 = 0; k0 < K; k0 += 64) {                                       \
        __syncthreads();                                                       \
        if (k0 + 64 < K) {                                                     \
            int nof = buf ^ 1;                                                 \
            _Pragma("unroll") for (int j = 0; j < 2; ++j)                      \
                async16(gA + (size_t)(j * 8) * K + k0 + 64,                    \
                        smem + nof * 4096 + ldsOfA + j * 512);                 \
            _Pragma("unroll") for (int j = 0; j < 4; ++j)                      \
                async16(gB + (size_t)(j * 8) * K + k0 + 64,                    \
                        smem + 8192 + nof * 8192 + ldsOfB + j * 512);          \
        }                                                                      \
        const bf16* sA = smem + buf * 4096;                                    \
        const bf16* sB = smem + 8192 + buf * 8192;                             \
        _Pragma("unroll") for (int kc = 0; kc < 2; ++kc) {                     \
            bf16x8 af[2], bq[4];                                               \
            int ch = ((kc << 2) + quad) ^ (l15 & 7);                           \
            _Pragma("unroll") for (int i = 0; i < 2; ++i)                      \
                af[i] = load_bf8(sA + (mb + i * 16 + l15) * 64 + ch * 8);      \
            _Pragma("unroll") for (int i = 0; i < 4; ++i)                      \
                bq[i] = load_bf8(sB + (nb + i * 16 + l15) * 64 + ch * 8);      \
            _Pragma("unroll") for (int mi = 0; mi < 2; ++mi)                   \
                _Pragma("unroll") for (int ni = 0; ni < 4; ++ni)               \
                    acc[mi][ni] = __builtin_amdgcn_mfma_f32_16x16x32_bf16(     \
                        af[mi], bq[ni], acc[mi][ni], 0, 0, 0);                 \
        }                                                                      \
        buf ^= 1;                                                              \
    }

// ====== QKV GEMM, fat-wave (r10 base) + fp32 B-staging with T14 split =======
// qkv pinned at 47-50us across 7 structural axes (r0-r11) -> schedule frozen.
// r12 change: B (weights) staged fp32->bf16 in-kernel. Per step per wave:
// 16 float4 loads issued BEFORE the MFMA cluster (pre[8][2], +64 VGPR),
// cvt + 8 ds_write_b128 AFTER it (T14 issue-early/write-late: HBM latency
// hides under 64 MFMA). Saves convert's 24MB fp32 weight pass (~7us).
// Identical numerics: same RNE cvt, same accumulation order.
__global__ __launch_bounds__(256, 1) void gemm_qkv_fused(
    const bf16* __restrict__ A, const float* __restrict__ wq,
    const float* __restrict__ wk, const float* __restrict__ wv,
    const float* __restrict__ qw, const float* __restrict__ kw,
    bf16* __restrict__ qb, bf16* __restrict__ kb, bf16* __restrict__ vtb) {
    const int K = 2048;
    int m0 = blockIdx.y * 128, n0 = blockIdx.x * 256;
    __shared__ __align__(16) bf16 smem[2 * 24576];  // 2 x (A 16KB + B 32KB)
    int tid = threadIdx.x;
    int lane = tid & 63, wid = tid >> 6;
    int l15 = lane & 15, quad = lane >> 4;
    int rlocal = lane >> 3;
    int scol = ((lane & 7) ^ rlocal) * 8;
    const bf16* gA = A + (size_t)(m0 + wid * 32 + rlocal) * K + scol;
    // per-block weight source (each 256-wide n-tile lies in one matrix)
    const float* Bsrc; int nb0;
    if (n0 < 2048)      { Bsrc = wq; nb0 = n0; }
    else if (n0 < 2560) { Bsrc = wk; nb0 = n0 - 2048; }
    else                { Bsrc = wv; nb0 = n0 - 2560; }
    const float* gBf = Bsrc + (size_t)(nb0 + wid * 64 + rlocal) * K + scol;
    int mb = (wid & 1) * 64, nb = (wid >> 1) * 128;

    floatx4 acc[4][8];
#pragma unroll
    for (int mi = 0; mi < 4; ++mi)
#pragma unroll
        for (int ni = 0; ni < 8; ++ni) acc[mi][ni] = floatx4{0.f, 0.f, 0.f, 0.f};

    // prologue: stage tile 0 (A async; B load+cvt+write, latency exposed once)
#pragma unroll
    for (int j = 0; j < 4; ++j)
        async16(gA + (size_t)(j * 8) * K, smem + (wid * 32 + j * 8) * 64);
#pragma unroll
    for (int j = 0; j < 8; ++j) {
        const float* s = gBf + (size_t)(j * 8) * K;
        float4 v0 = *reinterpret_cast<const float4*>(s);
        float4 v1 = *reinterpret_cast<const float4*>(s + 4);
        union { bf16 b[8]; bf16x8 v; } t;
        t.b[0] = (bf16)v0.x; t.b[1] = (bf16)v0.y;
        t.b[2] = (bf16)v0.z; t.b[3] = (bf16)v0.w;
        t.b[4] = (bf16)v1.x; t.b[5] = (bf16)v1.y;
        t.b[6] = (bf16)v1.z; t.b[7] = (bf16)v1.w;
        *reinterpret_cast<bf16x8*>(
            smem + 8192 + (wid * 64 + j * 8) * 64 + lane * 8) = t.v;
    }

    int buf = 0;
    for (int k0 = 0; k0 < K; k0 += 64) {
        __syncthreads();
        bool hasNext = (k0 + 64 < K);
        float4 pre[8][2];
        if (hasNext) {
            bf16* nbase = smem + (buf ^ 1) * 24576;
#pragma unroll
            for (int j = 0; j < 4; ++j)
                async16(gA + (size_t)(j * 8) * K + k0 + 64,
                        nbase + (wid * 32 + j * 8) * 64);
            // T14 issue-early: fp32 B loads for tile t+1, consumed post-MFMA
#pragma unroll
            for (int j = 0; j < 8; ++j) {
                const float* s = gBf + (size_t)(j * 8) * K + k0 + 64;
                pre[j][0] = *reinterpret_cast<const float4*>(s);
                pre[j][1] = *reinterpret_cast<const float4*>(s + 4);
            }
        }
        const bf16* sA = smem + buf * 24576;
        const bf16* sB = sA + 8192;
#pragma unroll
        for (int kc = 0; kc < 2; ++kc) {
            bf16x8 af[4], bq[8];
            int ch = ((kc << 2) + quad) ^ (l15 & 7);
#pragma unroll
            for (int i = 0; i < 4; ++i)
                af[i] = load_bf8(sA + (mb + i * 16 + l15) * 64 + ch * 8);
#pragma unroll
            for (int n = 0; n < 8; ++n)
                bq[n] = load_bf8(sB + (nb + n * 16 + l15) * 64 + ch * 8);
#pragma unroll
            for (int mi = 0; mi < 4; ++mi)
#pragma unroll
                for (int ni = 0; ni < 8; ++ni)
                    acc[mi][ni] = __builtin_amdgcn_mfma_f32_16x16x32_bf16(
                        af[mi], bq[ni], acc[mi][ni], 0, 0, 0);
        }
        if (hasNext) {
            // T14 write-late: cvt + ds_write into the non-read buffer
            bf16* nbase = smem + (buf ^ 1) * 24576;
#pragma unroll
            for (int j = 0; j < 8; ++j) {
                union { bf16 b[8]; bf16x8 v; } t;
                t.b[0] = (bf16)pre[j][0].x; t.b[1] = (bf16)pre[j][0].y;
                t.b[2] = (bf16)pre[j][0].z; t.b[3] = (bf16)pre[j][0].w;
                t.b[4] = (bf16)pre[j][1].x; t.b[5] = (bf16)pre[j][1].y;
                t.b[6] = (bf16)pre[j][1].z; t.b[7] = (bf16)pre[j][1].w;
                *reinterpret_cast<bf16x8*>(
                    nbase + 8192 + (wid * 64 + j * 8) * 64 + lane * 8) = t.v;
            }
        }
        buf ^= 1;
    }

    // ---- clip ----
#pragma unroll
    for (int mi = 0; mi < 4; ++mi)
#pragma unroll
        for (int ni = 0; ni < 8; ++ni)
#pragma unroll
            for (int r = 0; r < 4; ++r)
                acc[mi][ni][r] = fminf(fmaxf(acc[mi][ni][r], -8.0f), 8.0f);

    if (n0 >= 2560) {  // V: transpose-store, no norm/rope (block x=10,11)
#pragma unroll
        for (int mi = 0; mi < 4; ++mi)
#pragma unroll
            for (int ni = 0; ni < 8; ++ni)
#pragma unroll
                for (int r = 0; r < 4; ++r) {
                    int row = m0 + mb + mi * 16 + quad * 4 + r;
                    int n = n0 + nb + ni * 16 + l15;
                    vtb[(size_t)(n - 2560) * 2048 + row] = (bf16)acc[mi][ni][r];
                }
        return;
    }

    // ---- RMSNorm, fully in-register (wave owns all 128 cols of its head) ---
    const float* nw = (n0 < 2048) ? qw : kw;
    float nwv[8];
#pragma unroll
    for (int ni = 0; ni < 8; ++ni) nwv[ni] = nw[(nb + ni * 16 + l15) & 127];
#pragma unroll
    for (int mi = 0; mi < 4; ++mi)
#pragma unroll
        for (int r = 0; r < 4; ++r) {
            float s = 0.f;
#pragma unroll
            for (int ni = 0; ni < 8; ++ni) s += acc[mi][ni][r] * acc[mi][ni][r];
#pragma unroll
            for (int o = 1; o < 16; o <<= 1) s += __shfl_xor(s, o, 64);
            float rinv = rsqrtf(s * (1.0f / 128.0f) + 1e-6f);
#pragma unroll
            for (int ni = 0; ni < 8; ++ni) acc[mi][ni][r] *= rinv * nwv[ni];
        }

    // ---- RoPE (partner col^64 == ni^4, in-register; same angle) + store ----
    float invf[4];
#pragma unroll
    for (int ni = 0; ni < 4; ++ni) {
        int fi = ni * 16 + l15;  // (nb + ni*16 + l15) & 63, nb in {0,128}
        invf[ni] = __expf((float)fi * (-13.122363377404328f / 64.0f));
    }
#pragma unroll
    for (int mi = 0; mi < 4; ++mi)
#pragma unroll
        for (int r = 0; r < 4; ++r) {
            int row = mb + mi * 16 + quad * 4 + r;
            int s = m0 + row;
            float pos = (float)s;
#pragma unroll
            for (int ni = 0; ni < 4; ++ni) {
                float ang = pos * invf[ni];
                float c = __cosf(ang), sn = __sinf(ang);
                float a = acc[mi][ni][r], b2 = acc[mi][ni + 4][r];
                float olo = a * c - b2 * sn;
                float ohi = b2 * c + a * sn;
                int nlo = n0 + nb + ni * 16 + l15;
                if (n0 < 2048) {
                    qb[(size_t)s * 2048 + nlo] = (bf16)olo;
                    qb[(size_t)s * 2048 + nlo + 64] = (bf16)ohi;
                } else {
                    kb[(size_t)s * 512 + (nlo - 2048)] = (bf16)olo;
                    kb[(size_t)s * 512 + (nlo - 2048) + 64] = (bf16)ohi;
                }
            }
        }
}

// ---------- out-proj GEMM: 64x128 tile, BK=64, dbuf (fp32 out, r3) ---------
__global__ __launch_bounds__(256) void gemm_out(
    const bf16* __restrict__ A, const bf16* __restrict__ B,
    float* __restrict__ C) {
    const int K = 2048, N = 2048;
    int m0 = blockIdx.y * 64, n0 = blockIdx.x * 128;
    GEMM_BODY()
#pragma unroll
    for (int mi = 0; mi < 2; ++mi)
#pragma unroll
        for (int ni = 0; ni < 4; ++ni)
#pragma unroll
            for (int r = 0; r < 4; ++r) {
                int m = m0 + mb + mi * 16 + quad * 4 + r;
                int n = n0 + nb + ni * 16 + l15;
                C[(size_t)m * N + n] = acc[mi][ni][r];
            }
}

// -------- flash attention (r10: wo-convert ride + full-tile fast path) ------
__global__ __launch_bounds__(256) void attn(
    const bf16* __restrict__ qb, const bf16* __restrict__ kb,
    const bf16* __restrict__ vtb, const float* __restrict__ sinks,
    const float* __restrict__ wo, bf16* __restrict__ wob,
    bf16* __restrict__ attb) {
    __shared__ __align__(16) bf16 sK[2][64 * 128];   // 32 KB, swizzled
    __shared__ __align__(16) bf16 sV[2][128 * 64];   // 32 KB, swizzled
    __shared__ __align__(16) bf16 sP[64 * 72];       // 9 KB shared P, padded
    __shared__ float redu[64][4];                    // row-sum partials
    int tid = threadIdx.x;
    int lane = tid & 63, wid = tid >> 6;
    int l15 = lane & 15, quad = lane >> 4;
    int h = blockIdx.y, kh = h >> 2;
    int bq0 = blockIdx.x * 64;

    // ---- wo-convert prologue (512 blocks x 256 thr; 8 float4 each) ----
    {
        int bindex = blockIdx.y * gridDim.x + blockIdx.x;   // 0..511
        for (int i = bindex * 256 + tid; i < 1048576; i += 512 * 256) {
            float4 v = reinterpret_cast<const float4*>(wo)[i];
            union { bf16 b[4]; ushort4 u; } t2;
            t2.b[0] = (bf16)v.x; t2.b[1] = (bf16)v.y;
            t2.b[2] = (bf16)v.z; t2.b[3] = (bf16)v.w;
            reinterpret_cast<ushort4*>(wob)[i] = t2.u;
        }
    }

    // Q stationary: all 64 queries of this block, head h. frag[n=l15][k=quad*8+j]
    bf16x8 qf[4][4];
#pragma unroll
    for (int ni = 0; ni < 4; ++ni) {
        const bf16* qrow = qb + (size_t)(bq0 + ni * 16 + l15) * 2048 + h * 128 + quad * 8;
#pragma unroll
        for (int kc = 0; kc < 4; ++kc) qf[ni][kc] = load_bf8(qrow + kc * 32);
    }

    floatx4 acc[4][2];  // [mi][df]: 64 q x this wave's 32 dims
#pragma unroll
    for (int mi = 0; mi < 4; ++mi)
#pragma unroll
        for (int df = 0; df < 2; ++df) acc[mi][df] = floatx4{0.f, 0.f, 0.f, 0.f};
    float lpq[4];       // per-lane partial row sums (keys quad*4..+4 of wave)
#pragma unroll
    for (int ni = 0; ni < 4; ++ni) lpq[ni] = 0.f;

    // staging (XOR chunk swizzles; LDS dest forced = lane*16)
    int keyit = wid * 4 + (lane >> 4);
    int gcK = (lane & 15) ^ keyit;
    int dimit = wid * 8 + (lane >> 3);
    int gcV = (lane & 7) ^ ((lane >> 3) & 7);

    int tstart = bq0 - 1024; if (tstart < 0) tstart = 0;
    const bf16* kbase = kb + (size_t)kh * 128;
    const bf16* vbase = vtb + (size_t)kh * 128 * 2048;

#pragma unroll
    for (int r = 0; r < 4; ++r) {
        async16(kbase + (size_t)(tstart + r * 16 + keyit) * 512 + gcK * 8,
                sK[0] + (r * 16 + wid * 4) * 128);
        async16(vbase + (size_t)(r * 32 + dimit) * 2048 + tstart + gcV * 8,
                sV[0] + (r * 32 + wid * 8) * 64);
    }

    int buf = 0;
    for (int t = tstart; t <= bq0; t += 64) {
        __syncthreads();   // tile(buf) ready; sP from last iter fully consumed
        if (t + 64 <= bq0) {
#pragma unroll
            for (int r = 0; r < 4; ++r) {
                async16(kbase + (size_t)(t + 64 + r * 16 + keyit) * 512 + gcK * 8,
                        sK[buf ^ 1] + (r * 16 + wid * 4) * 128);
                async16(vbase + (size_t)(r * 32 + dimit) * 2048 + t + 64 + gcV * 8,
                        sV[buf ^ 1] + (r * 32 + wid * 8) * 64);
            }
        }
        // ---- phase 1: S^T = K·Q^T for this wave's 16 keys ----
        floatx4 ST[4];
#pragma unroll
        for (int ni = 0; ni < 4; ++ni) ST[ni] = floatx4{0.f, 0.f, 0.f, 0.f};
#pragma unroll
        for (int kc = 0; kc < 4; ++kc) {
            int ch = (kc * 4 + quad) ^ l15;  // row&15 == l15
            bf16x8 kf = load_bf8(sK[buf] + (wid * 16 + l15) * 128 + ch * 8);
#pragma unroll
            for (int ni = 0; ni < 4; ++ni)
                ST[ni] = __builtin_amdgcn_mfma_f32_16x16x32_bf16(kf, qf[ni][kc], ST[ni], 0, 0, 0);
        }
        int kbi = t + wid * 16 + quad * 4;  // this lane's first key
        // full tile: all (q,k) pass causal+window -> skip mask (wave-uniform)
        bool fullt = (t <= bq0 - 64) && (t >= bq0 - 960);
        if (fullt) {
#pragma unroll
            for (int ni = 0; ni < 4; ++ni) {
                bf16x4 pv;
#pragma unroll
                for (int r = 0; r < 4; ++r) {
                    float e = __expf(ST[ni][r] * 0.08838834764831845f);
                    lpq[ni] += e;
                    pv[r] = (bf16)e;
                }
                *(bf16x4*)(sP + (ni * 16 + l15) * 72 + wid * 16 + quad * 4) = pv;
            }
        } else {
#pragma unroll
            for (int ni = 0; ni < 4; ++ni) {
                int qi = bq0 + ni * 16 + l15;
                bf16x4 pv;
#pragma unroll
                for (int r = 0; r < 4; ++r) {
                    int ki = kbi + r;
                    float v = ST[ni][r] * 0.08838834764831845f;  // 1/sqrt(128)
                    bool ok = (ki <= qi) && (ki > qi - WINDOW);
                    float e = ok ? __expf(v) : 0.0f;
                    lpq[ni] += e;
                    pv[r] = (bf16)e;
                }
                *(bf16x4*)(sP + (ni * 16 + l15) * 72 + wid * 16 + quad * 4) = pv;
            }
        }
        __syncthreads();   // P complete
        // ---- phase 2: PV for this wave's 32 dims ----
#pragma unroll
        for (int kc = 0; kc < 2; ++kc) {
            bf16x8 pf[4];
#pragma unroll
            for (int mi = 0; mi < 4; ++mi)
                pf[mi] = load_bf8(sP + (mi * 16 + l15) * 72 + kc * 32 + quad * 8);
#pragma unroll
            for (int df = 0; df < 2; ++df) {
                int dim = wid * 32 + df * 16 + l15;
                int ch = (kc * 4 + quad) ^ (l15 & 7);
                bf16x8 vf = load_bf8(sV[buf] + dim * 64 + ch * 8);
#pragma unroll
                for (int mi = 0; mi < 4; ++mi)
                    acc[mi][df] = __builtin_amdgcn_mfma_f32_16x16x32_bf16(pf[mi], vf, acc[mi][df], 0, 0, 0);
            }
        }
        buf ^= 1;
    }

    // reduce lpq over the 4 key-subgroups (quad) of this wave, then cross-wave
#pragma unroll
    for (int ni = 0; ni < 4; ++ni) {
        float v = lpq[ni];
        v += __shfl_xor(v, 16, 64);
        v += __shfl_xor(v, 32, 64);
        if (quad == 0) redu[ni * 16 + l15][wid] = v;
    }
    __syncthreads();
    float sk = __expf(sinks[h]);
#pragma unroll
    for (int mi = 0; mi < 4; ++mi)
#pragma unroll
        for (int r = 0; r < 4; ++r) {
            int row = mi * 16 + quad * 4 + r;
            float rs = redu[row][0] + redu[row][1] + redu[row][2] + redu[row][3] + sk;
            float inv = 1.0f / rs;
#pragma unroll
            for (int df = 0; df < 2; ++df) {
                int dim = wid * 32 + df * 16 + l15;
                attb[(size_t)(bq0 + row) * 2048 + h * 128 + dim] =
                    (bf16)(acc[mi][df][r] * inv);
            }
        }
}

extern "C" void kernel_launch(void* const* d_in, const int* in_sizes, int n_in,
                              void* d_out, int out_size, void* d_ws, size_t ws_size,
                              hipStream_t stream) {
    const float* x      = (const float*)d_in[0];
    const float* w_q    = (const float*)d_in[1];
    const float* w_k    = (const float*)d_in[2];
    const float* w_v    = (const float*)d_in[3];
    const float* w_out  = (const float*)d_in[4];
    const float* q_norm = (const float*)d_in[5];
    const float* k_norm = (const float*)d_in[6];
    const float* sinks  = (const float*)d_in[7];

    char* ws = (char*)d_ws;
    const size_t MB = 1u << 20;
    bf16* xb   = (bf16*)(ws + 0 * MB);    // 8 MB
    bf16* wob  = (bf16*)(ws + 20 * MB);   // 8 MB (converted inside attn)
    bf16* qb   = (bf16*)(ws + 28 * MB);   // 8 MB  (post norm+rope)
    bf16* kb   = (bf16*)(ws + 36 * MB);   // 2 MB
    bf16* vtb  = (bf16*)(ws + 38 * MB);   // 2 MB  (V transposed)
    bf16* attb = (bf16*)(ws + 40 * MB);   // 8 MB
    float* out = (float*)d_out;

    convert_kernel<<<2048, 256, 0, stream>>>(x, xb);
    gemm_qkv_fused<<<dim3(12, 16), 256, 0, stream>>>(xb, w_q, w_k, w_v,
                                                     q_norm, k_norm,
                                                     qb, kb, vtb);
    attn<<<dim3(32, 16), 256, 0, stream>>>(qb, kb, vtb, sinks, w_out, wob, attb);
    gemm_out<<<dim3(16, 32), 256, 0, stream>>>(attb, wob, out);
}

// Round 13
// 201.393 us; speedup vs baseline: 1.3071x; 1.3071x over previous
//
#include <hip/hip_runtime.h>
#include <hip/hip_bf16.h>
#include <math.h>

#define S_LEN 2048
#define DMODEL 2048
#define NH 16
#define NKVH 4
#define HDIM 128
#define WINDOW 1024

typedef __bf16 bf16;
typedef __bf16 bf16x8 __attribute__((ext_vector_type(8)));
typedef __bf16 bf16x4 __attribute__((ext_vector_type(4)));
typedef float floatx4 __attribute__((ext_vector_type(4)));

static __device__ __forceinline__ bf16x8 load_bf8(const bf16* p) {
    return *reinterpret_cast<const bf16x8*>(p);
}

// async 16B global->LDS (wave-uniform LDS base + lane*16)
static __device__ __forceinline__ void async16(const bf16* g, bf16* l) {
    __builtin_amdgcn_global_load_lds(
        (const __attribute__((address_space(1))) void*)g,
        (__attribute__((address_space(3))) void*)l, 16, 0, 0);
}

// -------- fp32 -> bf16 conversion of x and QKV weights (wo rides in attn) ---
// r12 lesson: in-GEMM fp32 weight staging (T14 split) regressed 2.4x -- at
// 1 wave/SIMD there is no TLP to hide per-step register-staged load latency.
// Pre-converting at streaming BW is strictly better.
__global__ __launch_bounds__(256) void convert_kernel(
    const float* __restrict__ x, const float* __restrict__ wq,
    const float* __restrict__ wk, const float* __restrict__ wv,
    bf16* __restrict__ xb, bf16* __restrict__ wqb, bf16* __restrict__ wkb,
    bf16* __restrict__ wvb) {
    for (int i = blockIdx.x * blockDim.x + threadIdx.x; i < 2621440;
         i += gridDim.x * blockDim.x) {
        const float* src; bf16* dst; int off;
        if      (i < 1048576) { src = x;  dst = xb;  off = i; }
        else if (i < 2097152) { src = wq; dst = wqb; off = i - 1048576; }
        else if (i < 2359296) { src = wk; dst = wkb; off = i - 2097152; }
        else                  { src = wv; dst = wvb; off = i - 2359296; }
        float4 v = reinterpret_cast<const float4*>(src)[off];
        union { bf16 b[4]; ushort4 u; } t;
        t.b[0] = (bf16)v.x; t.b[1] = (bf16)v.y;
        t.b[2] = (bf16)v.z; t.b[3] = (bf16)v.w;
        reinterpret_cast<ushort4*>(dst)[off] = t.u;
    }
}

// ====== 64x128 tile, BK=64, dbuf GEMM body (r1-proven; gemm_out only) =======
#define GEMM_BODY()                                                            \
    __shared__ __align__(16) bf16 smem[2 * (64 + 128) * 64]; /* 48 KB */       \
    int tid = threadIdx.x;                                                     \
    int lane = tid & 63, wid = tid >> 6;                                       \
    int l15 = lane & 15, quad = lane >> 4;                                     \
    int rlocal = lane >> 3;                                                    \
    int scol = ((lane & 7) ^ rlocal) * 8;                                      \
    const bf16* gA = A + (size_t)(m0 + wid * 16 + rlocal) * K + scol;          \
    const bf16* gB = B + (size_t)(n0 + wid * 32 + rlocal) * K + scol;          \
    int ldsOfA = (wid * 16) * 64;                                               \
    int ldsOfB = (wid * 32) * 64;                                               \
    floatx4 acc[2][4];                                                         \
    _Pragma("unroll") for (int mi = 0; mi < 2; ++mi)                           \
        _Pragma("unroll") for (int ni = 0; ni < 4; ++ni)                       \
            acc[mi][ni] = floatx4{0.f, 0.f, 0.f, 0.f};                         \
    int mb = (wid & 1) * 32, nb = (wid >> 1) * 64;                             \
    _Pragma("unroll") for (int j = 0; j < 2; ++j)                              \
        async16(gA + (size_t)(j * 8) * K, smem + ldsOfA + j * 512);            \
    _Pragma("unroll") for (int j = 0; j < 4; ++j)                              \
        async16(gB + (size_t)(j * 8) * K, smem + 8192 + ldsOfB + j * 512);     \
    int buf = 0;                                                               \
    for (int k0 = 0; k0 < K; k0 += 64) {                                       \
        __syncthreads();                                                       \
        if (k0 + 64 < K) {                                                     \
            int nof = buf ^ 1;                                                 \
            _Pragma("unroll") for (int j = 0; j < 2; ++j)                      \
                async16(gA + (size_t)(j * 8) * K + k0 + 64,                    \
                        smem + nof * 4096 + ldsOfA + j * 512);                 \
            _Pragma("unroll") for (int j = 0; j < 4; ++j)                      \
                async16(gB + (size_t)(j * 8) * K + k0 + 64,                    \
                        smem + 8192 + nof * 8192 + ldsOfB + j * 512);          \
        }                                                                      \
        const bf16* sA = smem + buf * 4096;                                    \
        const bf16* sB = smem + 8192 + buf * 8192;                             \
        _Pragma("unroll") for (int kc = 0; kc < 2; ++kc) {                     \
            bf16x8 af[2], bq[4];                                               \
            int ch = ((kc << 2) + quad) ^ (l15 & 7);                           \
            _Pragma("unroll") for (int i = 0; i < 2; ++i)                      \
                af[i] = load_bf8(sA + (mb + i * 16 + l15) * 64 + ch * 8);      \
            _Pragma("unroll") for (int i = 0; i < 4; ++i)                      \
                bq[i] = load_bf8(sB + (nb + i * 16 + l15) * 64 + ch * 8);      \
            _Pragma("unroll") for (int mi = 0; mi < 2; ++mi)                   \
                _Pragma("unroll") for (int ni = 0; ni < 4; ++ni)               \
                    acc[mi][ni] = __builtin_amdgcn_mfma_f32_16x16x32_bf16(     \
                        af[mi], bq[ni], acc[mi][ni], 0, 0, 0);                 \
        }                                                                      \
        buf ^= 1;                                                              \
    }

// ====== QKV GEMM, FAT-WAVE: BM=128, BN=256, BK=64, 4 waves (r3, FROZEN) =====
// Pinned at 47-50us across SEVEN structural axes (r0-r11): occupancy 7-28%,
// 2-phase/8-phase/depth-2 schedules, XCD placement, 16/64-MFMA wave shapes,
// barrier styles, 16x16/32x32 MFMA shape. Latency-bound at the ~1.05GHz
// effective clock (MfmaUtil 20% <=> 553 TF = 51% of clock-derated ceiling).
__global__ __launch_bounds__(256, 1) void gemm_qkv_fused(
    const bf16* __restrict__ A, const bf16* __restrict__ B,
    const float* __restrict__ qw, const float* __restrict__ kw,
    bf16* __restrict__ qb, bf16* __restrict__ kb, bf16* __restrict__ vtb) {
    const int K = 2048;
    int m0 = blockIdx.y * 128, n0 = blockIdx.x * 256;
    __shared__ __align__(16) bf16 smem[2 * 24576];  // 2 x (A 16KB + B 32KB)
    int tid = threadIdx.x;
    int lane = tid & 63, wid = tid >> 6;
    int l15 = lane & 15, quad = lane >> 4;
    int rlocal = lane >> 3;
    int scol = ((lane & 7) ^ rlocal) * 8;
    const bf16* gA = A + (size_t)(m0 + wid * 32 + rlocal) * K + scol;
    const bf16* gB = B + (size_t)(n0 + wid * 64 + rlocal) * K + scol;
    int mb = (wid & 1) * 64, nb = (wid >> 1) * 128;

    floatx4 acc[4][8];
#pragma unroll
    for (int mi = 0; mi < 4; ++mi)
#pragma unroll
        for (int ni = 0; ni < 8; ++ni) acc[mi][ni] = floatx4{0.f, 0.f, 0.f, 0.f};

    // prologue: stage k-tile 0 into buf 0 (A: 4, B: 8 async16 per wave)
#pragma unroll
    for (int j = 0; j < 4; ++j)
        async16(gA + (size_t)(j * 8) * K, smem + (wid * 32 + j * 8) * 64);
#pragma unroll
    for (int j = 0; j < 8; ++j)
        async16(gB + (size_t)(j * 8) * K, smem + 8192 + (wid * 64 + j * 8) * 64);

    int buf = 0;
    for (int k0 = 0; k0 < K; k0 += 64) {
        __syncthreads();
        if (k0 + 64 < K) {
            bf16* nbase = smem + (buf ^ 1) * 24576;
#pragma unroll
            for (int j = 0; j < 4; ++j)
                async16(gA + (size_t)(j * 8) * K + k0 + 64,
                        nbase + (wid * 32 + j * 8) * 64);
#pragma unroll
            for (int j = 0; j < 8; ++j)
                async16(gB + (size_t)(j * 8) * K + k0 + 64,
                        nbase + 8192 + (wid * 64 + j * 8) * 64);
        }
        const bf16* sA = smem + buf * 24576;
        const bf16* sB = sA + 8192;
#pragma unroll
        for (int kc = 0; kc < 2; ++kc) {
            bf16x8 af[4], bq[8];
            int ch = ((kc << 2) + quad) ^ (l15 & 7);
#pragma unroll
            for (int i = 0; i < 4; ++i)
                af[i] = load_bf8(sA + (mb + i * 16 + l15) * 64 + ch * 8);
#pragma unroll
            for (int n = 0; n < 8; ++n)
                bq[n] = load_bf8(sB + (nb + n * 16 + l15) * 64 + ch * 8);
#pragma unroll
            for (int mi = 0; mi < 4; ++mi)
#pragma unroll
                for (int ni = 0; ni < 8; ++ni)
                    acc[mi][ni] = __builtin_amdgcn_mfma_f32_16x16x32_bf16(
                        af[mi], bq[ni], acc[mi][ni], 0, 0, 0);
        }
        buf ^= 1;
    }

    // ---- clip ----
#pragma unroll
    for (int mi = 0; mi < 4; ++mi)
#pragma unroll
        for (int ni = 0; ni < 8; ++ni)
#pragma unroll
            for (int r = 0; r < 4; ++r)
                acc[mi][ni][r] = fminf(fmaxf(acc[mi][ni][r], -8.0f), 8.0f);

    if (n0 >= 2560) {  // V: transpose-store, no norm/rope (block x=10,11)
#pragma unroll
        for (int mi = 0; mi < 4; ++mi)
#pragma unroll
            for (int ni = 0; ni < 8; ++ni)
#pragma unroll
                for (int r = 0; r < 4; ++r) {
                    int row = m0 + mb + mi * 16 + quad * 4 + r;
                    int n = n0 + nb + ni * 16 + l15;
                    vtb[(size_t)(n - 2560) * 2048 + row] = (bf16)acc[mi][ni][r];
                }
        return;
    }

    // ---- RMSNorm, fully in-register (wave owns all 128 cols of its head) ---
    const float* nw = (n0 < 2048) ? qw : kw;
    float nwv[8];
#pragma unroll
    for (int ni = 0; ni < 8; ++ni) nwv[ni] = nw[(nb + ni * 16 + l15) & 127];
#pragma unroll
    for (int mi = 0; mi < 4; ++mi)
#pragma unroll
        for (int r = 0; r < 4; ++r) {
            float s = 0.f;
#pragma unroll
            for (int ni = 0; ni < 8; ++ni) s += acc[mi][ni][r] * acc[mi][ni][r];
#pragma unroll
            for (int o = 1; o < 16; o <<= 1) s += __shfl_xor(s, o, 64);
            float rinv = rsqrtf(s * (1.0f / 128.0f) + 1e-6f);
#pragma unroll
            for (int ni = 0; ni < 8; ++ni) acc[mi][ni][r] *= rinv * nwv[ni];
        }

    // ---- RoPE (partner col^64 == ni^4, in-register; same angle) + store ----
    float invf[4];
#pragma unroll
    for (int ni = 0; ni < 4; ++ni) {
        int fi = ni * 16 + l15;  // (nb + ni*16 + l15) & 63, nb in {0,128}
        invf[ni] = __expf((float)fi * (-13.122363377404328f / 64.0f));
    }
#pragma unroll
    for (int mi = 0; mi < 4; ++mi)
#pragma unroll
        for (int r = 0; r < 4; ++r) {
            int row = mb + mi * 16 + quad * 4 + r;
            int s = m0 + row;
            float pos = (float)s;
#pragma unroll
            for (int ni = 0; ni < 4; ++ni) {
                float ang = pos * invf[ni];
                float c = __cosf(ang), sn = __sinf(ang);
                float a = acc[mi][ni][r], b2 = acc[mi][ni + 4][r];
                float olo = a * c - b2 * sn;
                float ohi = b2 * c + a * sn;
                int nlo = n0 + nb + ni * 16 + l15;
                if (n0 < 2048) {
                    qb[(size_t)s * 2048 + nlo] = (bf16)olo;
                    qb[(size_t)s * 2048 + nlo + 64] = (bf16)ohi;
                } else {
                    kb[(size_t)s * 512 + (nlo - 2048)] = (bf16)olo;
                    kb[(size_t)s * 512 + (nlo - 2048) + 64] = (bf16)ohi;
                }
            }
        }
}

// ---------- out-proj GEMM: 64x128 tile, BK=64, dbuf (fp32 out, r3) ---------
__global__ __launch_bounds__(256) void gemm_out(
    const bf16* __restrict__ A, const bf16* __restrict__ B,
    float* __restrict__ C) {
    const int K = 2048, N = 2048;
    int m0 = blockIdx.y * 64, n0 = blockIdx.x * 128;
    GEMM_BODY()
#pragma unroll
    for (int mi = 0; mi < 2; ++mi)
#pragma unroll
        for (int ni = 0; ni < 4; ++ni)
#pragma unroll
            for (int r = 0; r < 4; ++r) {
                int m = m0 + mb + mi * 16 + quad * 4 + r;
                int n = n0 + nb + ni * 16 + l15;
                C[(size_t)m * N + n] = acc[mi][ni][r];
            }
}

// -------- flash attention (r10: wo-convert ride + full-tile fast path) ------
__global__ __launch_bounds__(256) void attn(
    const bf16* __restrict__ qb, const bf16* __restrict__ kb,
    const bf16* __restrict__ vtb, const float* __restrict__ sinks,
    const float* __restrict__ wo, bf16* __restrict__ wob,
    bf16* __restrict__ attb) {
    __shared__ __align__(16) bf16 sK[2][64 * 128];   // 32 KB, swizzled
    __shared__ __align__(16) bf16 sV[2][128 * 64];   // 32 KB, swizzled
    __shared__ __align__(16) bf16 sP[64 * 72];       // 9 KB shared P, padded
    __shared__ float redu[64][4];                    // row-sum partials
    int tid = threadIdx.x;
    int lane = tid & 63, wid = tid >> 6;
    int l15 = lane & 15, quad = lane >> 4;
    int h = blockIdx.y, kh = h >> 2;
    int bq0 = blockIdx.x * 64;

    // ---- wo-convert prologue (512 blocks x 256 thr; 8 float4 each) ----
    // wo is only consumed by gemm_out (later on the stream) -> its 25MB of
    // traffic overlaps attn's compute-bound body for free.
    {
        int bindex = blockIdx.y * gridDim.x + blockIdx.x;   // 0..511
        for (int i = bindex * 256 + tid; i < 1048576; i += 512 * 256) {
            float4 v = reinterpret_cast<const float4*>(wo)[i];
            union { bf16 b[4]; ushort4 u; } t2;
            t2.b[0] = (bf16)v.x; t2.b[1] = (bf16)v.y;
            t2.b[2] = (bf16)v.z; t2.b[3] = (bf16)v.w;
            reinterpret_cast<ushort4*>(wob)[i] = t2.u;
        }
    }

    // Q stationary: all 64 queries of this block, head h. frag[n=l15][k=quad*8+j]
    bf16x8 qf[4][4];
#pragma unroll
    for (int ni = 0; ni < 4; ++ni) {
        const bf16* qrow = qb + (size_t)(bq0 + ni * 16 + l15) * 2048 + h * 128 + quad * 8;
#pragma unroll
        for (int kc = 0; kc < 4; ++kc) qf[ni][kc] = load_bf8(qrow + kc * 32);
    }

    floatx4 acc[4][2];  // [mi][df]: 64 q x this wave's 32 dims
#pragma unroll
    for (int mi = 0; mi < 4; ++mi)
#pragma unroll
        for (int df = 0; df < 2; ++df) acc[mi][df] = floatx4{0.f, 0.f, 0.f, 0.f};
    float lpq[4];       // per-lane partial row sums (keys quad*4..+4 of wave)
#pragma unroll
    for (int ni = 0; ni < 4; ++ni) lpq[ni] = 0.f;

    // staging (XOR chunk swizzles; LDS dest forced = lane*16)
    int keyit = wid * 4 + (lane >> 4);
    int gcK = (lane & 15) ^ keyit;
    int dimit = wid * 8 + (lane >> 3);
    int gcV = (lane & 7) ^ ((lane >> 3) & 7);

    int tstart = bq0 - 1024; if (tstart < 0) tstart = 0;
    const bf16* kbase = kb + (size_t)kh * 128;
    const bf16* vbase = vtb + (size_t)kh * 128 * 2048;

#pragma unroll
    for (int r = 0; r < 4; ++r) {
        async16(kbase + (size_t)(tstart + r * 16 + keyit) * 512 + gcK * 8,
                sK[0] + (r * 16 + wid * 4) * 128);
        async16(vbase + (size_t)(r * 32 + dimit) * 2048 + tstart + gcV * 8,
                sV[0] + (r * 32 + wid * 8) * 64);
    }

    int buf = 0;
    for (int t = tstart; t <= bq0; t += 64) {
        __syncthreads();   // tile(buf) ready; sP from last iter fully consumed
        if (t + 64 <= bq0) {
#pragma unroll
            for (int r = 0; r < 4; ++r) {
                async16(kbase + (size_t)(t + 64 + r * 16 + keyit) * 512 + gcK * 8,
                        sK[buf ^ 1] + (r * 16 + wid * 4) * 128);
                async16(vbase + (size_t)(r * 32 + dimit) * 2048 + t + 64 + gcV * 8,
                        sV[buf ^ 1] + (r * 32 + wid * 8) * 64);
            }
        }
        // ---- phase 1: S^T = K·Q^T for this wave's 16 keys ----
        floatx4 ST[4];
#pragma unroll
        for (int ni = 0; ni < 4; ++ni) ST[ni] = floatx4{0.f, 0.f, 0.f, 0.f};
#pragma unroll
        for (int kc = 0; kc < 4; ++kc) {
            int ch = (kc * 4 + quad) ^ l15;  // row&15 == l15
            bf16x8 kf = load_bf8(sK[buf] + (wid * 16 + l15) * 128 + ch * 8);
#pragma unroll
            for (int ni = 0; ni < 4; ++ni)
                ST[ni] = __builtin_amdgcn_mfma_f32_16x16x32_bf16(kf, qf[ni][kc], ST[ni], 0, 0, 0);
        }
        int kbi = t + wid * 16 + quad * 4;  // this lane's first key
        // full tile: all (q,k) pass causal+window -> skip mask (wave-uniform)
        bool fullt = (t <= bq0 - 64) && (t >= bq0 - 960);
        if (fullt) {
#pragma unroll
            for (int ni = 0; ni < 4; ++ni) {
                bf16x4 pv;
#pragma unroll
                for (int r = 0; r < 4; ++r) {
                    float e = __expf(ST[ni][r] * 0.08838834764831845f);
                    lpq[ni] += e;
                    pv[r] = (bf16)e;
                }
                *(bf16x4*)(sP + (ni * 16 + l15) * 72 + wid * 16 + quad * 4) = pv;
            }
        } else {
#pragma unroll
            for (int ni = 0; ni < 4; ++ni) {
                int qi = bq0 + ni * 16 + l15;
                bf16x4 pv;
#pragma unroll
                for (int r = 0; r < 4; ++r) {
                    int ki = kbi + r;
                    float v = ST[ni][r] * 0.08838834764831845f;  // 1/sqrt(128)
                    bool ok = (ki <= qi) && (ki > qi - WINDOW);
                    float e = ok ? __expf(v) : 0.0f;
                    lpq[ni] += e;
                    pv[r] = (bf16)e;
                }
                *(bf16x4*)(sP + (ni * 16 + l15) * 72 + wid * 16 + quad * 4) = pv;
            }
        }
        __syncthreads();   // P complete
        // ---- phase 2: PV for this wave's 32 dims ----
#pragma unroll
        for (int kc = 0; kc < 2; ++kc) {
            bf16x8 pf[4];
#pragma unroll
            for (int mi = 0; mi < 4; ++mi)
                pf[mi] = load_bf8(sP + (mi * 16 + l15) * 72 + kc * 32 + quad * 8);
#pragma unroll
            for (int df = 0; df < 2; ++df) {
                int dim = wid * 32 + df * 16 + l15;
                int ch = (kc * 4 + quad) ^ (l15 & 7);
                bf16x8 vf = load_bf8(sV[buf] + dim * 64 + ch * 8);
#pragma unroll
                for (int mi = 0; mi < 4; ++mi)
                    acc[mi][df] = __builtin_amdgcn_mfma_f32_16x16x32_bf16(pf[mi], vf, acc[mi][df], 0, 0, 0);
            }
        }
        buf ^= 1;
    }

    // reduce lpq over the 4 key-subgroups (quad) of this wave, then cross-wave
#pragma unroll
    for (int ni = 0; ni < 4; ++ni) {
        float v = lpq[ni];
        v += __shfl_xor(v, 16, 64);
        v += __shfl_xor(v, 32, 64);
        if (quad == 0) redu[ni * 16 + l15][wid] = v;
    }
    __syncthreads();
    float sk = __expf(sinks[h]);
#pragma unroll
    for (int mi = 0; mi < 4; ++mi)
#pragma unroll
        for (int r = 0; r < 4; ++r) {
            int row = mi * 16 + quad * 4 + r;
            float rs = redu[row][0] + redu[row][1] + redu[row][2] + redu[row][3] + sk;
            float inv = 1.0f / rs;
#pragma unroll
            for (int df = 0; df < 2; ++df) {
                int dim = wid * 32 + df * 16 + l15;
                attb[(size_t)(bq0 + row) * 2048 + h * 128 + dim] =
                    (bf16)(acc[mi][df][r] * inv);
            }
        }
}

extern "C" void kernel_launch(void* const* d_in, const int* in_sizes, int n_in,
                              void* d_out, int out_size, void* d_ws, size_t ws_size,
                              hipStream_t stream) {
    const float* x      = (const float*)d_in[0];
    const float* w_q    = (const float*)d_in[1];
    const float* w_k    = (const float*)d_in[2];
    const float* w_v    = (const float*)d_in[3];
    const float* w_out  = (const float*)d_in[4];
    const float* q_norm = (const float*)d_in[5];
    const float* k_norm = (const float*)d_in[6];
    const float* sinks  = (const float*)d_in[7];

    char* ws = (char*)d_ws;
    const size_t MB = 1u << 20;
    bf16* xb   = (bf16*)(ws + 0 * MB);    // 8 MB
    bf16* wqb  = (bf16*)(ws + 8 * MB);    // 8 MB  (wqb/wkb/wvb contiguous)
    bf16* wkb  = (bf16*)(ws + 16 * MB);   // 2 MB  (forms wcomb [3072][2048])
    bf16* wvb  = (bf16*)(ws + 18 * MB);   // 2 MB
    bf16* wob  = (bf16*)(ws + 20 * MB);   // 8 MB (converted inside attn)
    bf16* qb   = (bf16*)(ws + 28 * MB);   // 8 MB  (post norm+rope)
    bf16* kb   = (bf16*)(ws + 36 * MB);   // 2 MB
    bf16* vtb  = (bf16*)(ws + 38 * MB);   // 2 MB  (V transposed)
    bf16* attb = (bf16*)(ws + 40 * MB);   // 8 MB
    bf16* wcomb = wqb;                    // rows 0..3071 = [w_q; w_k; w_v]
    float* out = (float*)d_out;

    convert_kernel<<<2048, 256, 0, stream>>>(x, w_q, w_k, w_v,
                                             xb, wqb, wkb, wvb);
    gemm_qkv_fused<<<dim3(12, 16), 256, 0, stream>>>(xb, wcomb, q_norm, k_norm,
                                                     qb, kb, vtb);
    attn<<<dim3(32, 16), 256, 0, stream>>>(qb, kb, vtb, sinks, w_out, wob, attb);
    gemm_out<<<dim3(16, 32), 256, 0, stream>>>(attb, wob, out);
}